// Round 3
// baseline (412.592 us; speedup 1.0000x reference)
//
#include <hip/hip_runtime.h>

typedef float v4f __attribute__((ext_vector_type(4)));

#define BATCH 16384
#define NS    5
#define NCTX  10
#define XSTR  (NCTX + 2)
#define D4    75          // 300 floats = 75 float4; rows are 1200B -> 16B aligned
#define NBLK  4096        // 4096 blocks x 4 waves = 16384 waves = 1 row per wave

// One wave per batch row. Lane l owns float4 chunk l, plus chunk 64+l for
// l < 11. __launch_bounds__(256,8) caps VGPRs at 64 -> full 32 waves/CU
// residency to hide ~900-cycle gather latency. Ws (300 MB, ~no reuse) is
// streamed with non-temporal loads so it doesn't evict the hot 60 MB Wg
// table from L2/L3.
__global__ __launch_bounds__(256, 8) void sense_partials(
    const int*   __restrict__ x,
    const float* __restrict__ Wg,
    const float* __restrict__ Ws,
    float*       __restrict__ partial /* [NS][NBLK] */) {
  const int lane = threadIdx.x & 63;
  const int wid  = threadIdx.x >> 6;          // 4 waves per block
  const int b    = blockIdx.x * 4 + wid;      // one row per wave

  const v4f* Wg4 = (const v4f*)Wg;
  const v4f* Ws4 = (const v4f*)Ws;

  int v = (lane < XSTR) ? x[(size_t)b * XSTR + lane] : 0;
  const int w0 = __shfl(v, 0);
  const v4f* wrow = Ws4 + (size_t)w0 * (NS * D4);

  const bool hi = (lane < D4 - 64);           // lanes 0..10 own chunk 64+lane

  v4f sc0 = 0.f, sc1 = 0.f;
#pragma unroll
  for (int j = 0; j < NCTX; ++j) {
    const int c = __shfl(v, 2 + j);
    const v4f* r = Wg4 + (size_t)c * D4;
    sc0 += r[lane];
    if (hi) sc1 += r[64 + lane];
  }

  float acc[NS];
#pragma unroll
  for (int s = 0; s < NS; ++s) {
    v4f a0 = __builtin_nontemporal_load(&wrow[s * D4 + lane]);
    v4f p  = a0 * sc0;
    if (hi) {
      v4f a1 = __builtin_nontemporal_load(&wrow[s * D4 + 64 + lane]);
      p += a1 * sc1;
    }
    acc[s] = p.x + p.y + p.z + p.w;
  }

  // wave reduction (64 lanes)
#pragma unroll
  for (int s = 0; s < NS; ++s) {
    float t = acc[s];
#pragma unroll
    for (int off = 32; off; off >>= 1) t += __shfl_down(t, off);
    acc[s] = t;
  }

  __shared__ float red[4][NS];
  if (lane == 0) {
#pragma unroll
    for (int s = 0; s < NS; ++s) red[wid][s] = acc[s];
  }
  __syncthreads();
  if (threadIdx.x < NS) {
    float t = red[0][threadIdx.x] + red[1][threadIdx.x] +
              red[2][threadIdx.x] + red[3][threadIdx.x];
    partial[threadIdx.x * NBLK + blockIdx.x] = t;   // s-major for easy reduce
  }
}

// Kernel 2: 5 waves, wave s reduces partial[s][*], writes sigmoid.
__global__ __launch_bounds__(320) void sense_reduce(
    const float* __restrict__ partial, float* __restrict__ out) {
  const int lane = threadIdx.x & 63;
  const int s    = threadIdx.x >> 6;   // 0..4
  float sum = 0.f;
  for (int g = lane; g < NBLK; g += 64) sum += partial[s * NBLK + g];
#pragma unroll
  for (int off = 32; off; off >>= 1) sum += __shfl_down(sum, off);
  if (lane == 0) out[s] = 1.0f / (1.0f + __expf(-sum));
}

extern "C" void kernel_launch(void* const* d_in, const int* in_sizes, int n_in,
                              void* d_out, int out_size, void* d_ws, size_t ws_size,
                              hipStream_t stream) {
  const int*   x  = (const int*)d_in[0];
  const float* Wg = (const float*)d_in[1];
  const float* Ws = (const float*)d_in[2];
  float* partial  = (float*)d_ws;          // NS*NBLK*4 = 80 KB
  float* out      = (float*)d_out;

  sense_partials<<<NBLK, 256, 0, stream>>>(x, Wg, Ws, partial);
  sense_reduce<<<1, 320, 0, stream>>>(partial, out);
}